// Round 2
// baseline (296.741 us; speedup 1.0000x reference)
//
#include <hip/hip_runtime.h>
#include <math.h>

typedef __bf16 bf16;
typedef __attribute__((ext_vector_type(8))) __bf16 bf16x8;
typedef __attribute__((ext_vector_type(4))) float f32x4;

// ---------------------------------------------------------------------------
// B=16, L=1024, U=512, H=2. M = 16384. fp32 I/O, bf16 internal.
// R12 (= R11 resubmit after container infra failure): dual GEMMs on the
// 256x256 8-wave 4-phase/K-tile schedule (T2 granule-swizzle + T3/T4 counted
// vmcnt(6) + T5 setprio). 256 blocks x 512 thr, 128KB dbuf LDS, loads stay
// in flight across barriers. gemm_nt (scores/PV) unchanged.
// ---------------------------------------------------------------------------

__device__ __forceinline__ void load_lds16(const bf16* g, bf16* l) {
  __builtin_amdgcn_global_load_lds(
      (const __attribute__((address_space(1))) unsigned int*)(g),
      (__attribute__((address_space(3))) unsigned int*)(l), 16, 0, 0);
}

// ============================ plain NT GEMM ================================
struct GemmArgs {
  const bf16* A; const bf16* B; bf16* C;
  int K, lda, ldb, ldc;
  long long Ab, Bb, Cb;
  const float* s1; const float* s2; const float* abp; // EPI1; s1=lsum for EPI4
  float* lsum;                   // EPI 1: row sums of E
  int L;
  int gxsh, gysh;
};

// C[M,N] = A[M,K] @ Bt[N,K]^T. Tile 128xTN, BK=64, 4 waves 2x2 (wave tile
// 64 x TN/2), MFMA 16x16x32. global_load_lds w=16, XOR-swizzled granules
// (0 bank conflicts, R4-verified). XCD swizzle for L2 locality (R4-verified).
template<int EPI, int TN>   // EPI: 1 = scores->E + lsum atomics, 4 = PV*(1/l)
__global__ __launch_bounds__(256, 4)
void gemm_nt(GemmArgs g) {
  constexpr int JN = TN / 32;            // B j-frags per wave; B chunks/quarter
  __shared__ bf16 As[128 * 64];
  __shared__ bf16 Bs[TN * 64];
  const int tid = threadIdx.x;
  const int bid = blockIdx.x;
  const int xcd = bid & 7;
  const int t = bid >> 3;
  const int bx = t & ((1 << g.gxsh) - 1);
  const int r  = t >> g.gxsh;
  const int Rx = gridDim.x >> (3 + g.gxsh);
  const int gr = xcd * Rx + r;
  const int by = gr & ((1 << g.gysh) - 1);
  const int bz = gr >> g.gysh;

  const bf16* Ag = g.A + (long long)bz * g.Ab + (long long)(by * 128) * g.lda;
  const bf16* Bg = g.B + (long long)bz * g.Bb + (long long)(bx * TN) * g.ldb;
  const int wid = tid >> 6, lane = tid & 63;
  const int wm = (wid >> 1) << 6;
  const int wn = (wid & 1) * (TN / 2);
  const int lr = lane & 15, lq = lane >> 4;

  f32x4 acc[4][JN];
#pragma unroll
  for (int i = 0; i < 4; i++)
#pragma unroll
    for (int j = 0; j < JN; j++) acc[i][j] = f32x4{0.f, 0.f, 0.f, 0.f};

  const int srow8 = (tid >> 3) & 7;
  const int skc   = (tid & 7) ^ srow8;
  const int lswz  = (lr & 7);

  for (int k0 = 0; k0 < g.K; k0 += 64) {
    __syncthreads();
#pragma unroll
    for (int j = 0; j < 4; j++) {
      const int ci = (tid >> 6) * 4 + j;
      const int row = ci * 8 + srow8;
      load_lds16(Ag + (long long)row * g.lda + k0 + skc * 8, As + ci * 512);
    }
#pragma unroll
    for (int j = 0; j < JN; j++) {
      const int ci = (tid >> 6) * JN + j;
      const int row = ci * 8 + srow8;
      load_lds16(Bg + (long long)row * g.ldb + k0 + skc * 8, Bs + ci * 512);
    }
    __syncthreads();
#pragma unroll
    for (int ks = 0; ks < 2; ks++) {
      bf16x8 af[4], bfr[JN];
      const int kx = (ks * 4 + lq) ^ lswz;
#pragma unroll
      for (int i = 0; i < 4; i++)
        af[i] = *(const bf16x8*)(&As[(wm + i * 16 + lr) * 64 + kx * 8]);
#pragma unroll
      for (int j = 0; j < JN; j++)
        bfr[j] = *(const bf16x8*)(&Bs[(wn + j * 16 + lr) * 64 + kx * 8]);
#pragma unroll
      for (int i = 0; i < 4; i++)
#pragma unroll
        for (int j = 0; j < JN; j++)
          acc[i][j] = __builtin_amdgcn_mfma_f32_16x16x32_bf16(af[i], bfr[j], acc[i][j], 0, 0, 0);
    }
  }

  bf16* Cg = g.C + (long long)bz * g.Cb;
#pragma unroll
  for (int i = 0; i < 4; i++) {
#pragma unroll
    for (int v = 0; v < 4; v++) {
      int row = by * 128 + wm + i * 16 + lq * 4 + v;
      float srow = 0.f;
      if (EPI == 1) srow = g.s1[bz * g.L + row] + g.abp[0];
      if (EPI == 4) srow = 1.f / g.s1[bz * g.L + row];   // reciprocal of lsum
      float psum = 0.f;
#pragma unroll
      for (int j = 0; j < JN; j++) {
        int col = bx * TN + wn + j * 16 + lr;
        float val = acc[i][j][v];
        if (EPI == 1) {
          val += srow + g.s2[bz * g.L + col];
          val = fminf(fmaxf(val, 0.f), 60.f);
          val = __expf(val);
          bf16 eb = (bf16)val;
          psum += (float)eb;
          Cg[(long long)row * g.ldc + col] = eb;
        } else {
          val *= srow;
          Cg[(long long)row * g.ldc + col] = (bf16)val;
        }
      }
      if (EPI == 1) {
        psum += __shfl_xor(psum, 1, 64);
        psum += __shfl_xor(psum, 2, 64);
        psum += __shfl_xor(psum, 4, 64);
        psum += __shfl_xor(psum, 8, 64);
        if (lr == 0) atomicAdd(&g.lsum[bz * g.L + row], psum);
      }
    }
  }
}

// ================ dual-column fused-gating GEMM, 8-phase ===================
// 256x256 tile (256 M-rows x [128 t-cols + 128 c-cols]), BK=64, 8 waves
// (2M x 4N), per-wave 128x64, MFMA 16x16x32. Double-buffered 128KB LDS,
// 4 phases per K-tile, one half-tile staged per phase, vmcnt(6) once per
// K-tile (3 half-tiles in flight), s_setprio around each 16-MFMA cluster.
struct DualArgs {
  const bf16* A; const bf16* A2;   // A2 = rows for k>=512 (final); else == A
  const bf16* Bt;
  void* C; const void* xres;
  const float* bias_t; const float* bias_c;
  int K, ldb;
  const float* aW;                 // EPI 2
  float* s1a; float* s2a;          // EPI 2: atomic partial dots
  bf16* q;                         // EPI 2: x * w3
  bf16* xT;                        // EPI 2: per-batch transpose of x2
};

template<int EPI>  // 0 = highway, 2 = highway + s1/s2/q/xT fusion, 1 = final
__global__ __launch_bounds__(512, 2)
void gemm_dual8(DualArgs g) {
  // [buf][ A: 16384 bf16 (256x64) | B: 16384 bf16 (256x64) ]
  __shared__ __align__(16) bf16 smem[2][32768];
  const int tid = threadIdx.x;
  const int bid = blockIdx.x;
  const int xcd = bid & 7;
  const int t = bid >> 3;
  const int bx = t & 3;               // 128-wide dual col tile (4 total)
  const int by = xcd * 8 + (t >> 2);  // 0..63 M-tile, XCD-contiguous
  const int wid = tid >> 6, lane = tid & 63;
  const int wr = wid >> 2, wc = wid & 3;
  const int lr = lane & 15, lq = lane >> 4;
  const int lswz = lr & 7;
  const int srow8 = (lane >> 3) & 7;
  const int skc = (lane & 7) ^ srow8;
  const long long abase = (long long)(by * 256) * 512;
  const int NT = g.K >> 6;

  f32x4 acc[8][4];
#pragma unroll
  for (int i = 0; i < 8; i++)
#pragma unroll
    for (int j = 0; j < 4; j++) acc[i][j] = f32x4{0.f, 0.f, 0.f, 0.f};

  // ---- staging: one half-tile = 16 chunks of (8 rows x 64 k); each thread
  // issues 2 global_load_lds (wave covers 2 chunks). A halves contiguous
  // (h0 = rows 0..127). B halves strided ((c&7)<4 == the region read in P1)
  // so P2's stage only touches what P1 consumed.
  auto stage_a = [&](int kt, int b, int h) {
    const bf16* Ak = (kt < 8) ? g.A : g.A2;
    const int kk = (kt & 7) << 6;
#pragma unroll
    for (int jj = 0; jj < 2; jj++) {
      const int c = h * 16 + wid * 2 + jj;             // 0..31
      const int row = c * 8 + srow8;
      load_lds16(Ak + abase + (long long)row * 512 + kk + skc * 8,
                 &smem[b][c * 512]);
    }
  };
  auto stage_b = [&](int kt, int b, int h) {
    const int k0 = kt << 6;
#pragma unroll
    for (int jj = 0; jj < 2; jj++) {
      const int ci = wid * 2 + jj;                     // 0..15
      const int c = ((ci >> 2) << 3) + (h << 2) + (ci & 3);  // strided halves
      const int bn = c * 8 + srow8;
      const int grp = bn >> 5, r5 = bn & 31;
      const int grow = ((grp & 1) << 9) + bx * 128 + ((grp >> 1) << 5) + r5;
      load_lds16(g.Bt + (long long)grow * g.ldb + k0 + skc * 8,
                 &smem[b][16384 + c * 512]);
    }
  };
  auto ldA = [&](int b, int i, int ks) -> bf16x8 {
    const int kx = (ks * 4 + lq) ^ lswz;
    return *(const bf16x8*)(&smem[b][(wr * 128 + i * 16 + lr) * 64 + kx * 8]);
  };
  auto ldB = [&](int b, int j, int ks) -> bf16x8 {
    const int kx = (ks * 4 + lq) ^ lswz;
    return *(const bf16x8*)(&smem[b][16384 + (wc * 64 + j * 16 + lr) * 64 + kx * 8]);
  };

  // prologue: kt0 fully (4 half-tiles), kt1 all but A-hi (3 half-tiles).
  stage_b(0, 0, 0); stage_b(0, 0, 1); stage_a(0, 0, 0); stage_a(0, 0, 1);
  stage_b(1, 1, 0); stage_b(1, 1, 1); stage_a(1, 1, 0);
  asm volatile("s_waitcnt vmcnt(6)" ::: "memory");   // kt0's 8 loads landed
  __builtin_amdgcn_s_barrier();

  for (int kt = 0; kt < NT; kt++) {
    const int cur = kt & 1, nxt = cur ^ 1;
    bf16x8 af[4][2], b01[2][2], b23[2][2];
    // ---- P1: stage A-hi(kt+1); read A q0 + B01; MFMA (i0-3 x j0-1)
    if (kt + 1 < NT) stage_a(kt + 1, nxt, 1);
#pragma unroll
    for (int i = 0; i < 4; i++)
#pragma unroll
      for (int ks = 0; ks < 2; ks++) af[i][ks] = ldA(cur, i, ks);
#pragma unroll
    for (int j = 0; j < 2; j++)
#pragma unroll
      for (int ks = 0; ks < 2; ks++) b01[j][ks] = ldB(cur, j, ks);
    __builtin_amdgcn_s_barrier();
    __builtin_amdgcn_s_setprio(1);
#pragma unroll
    for (int i = 0; i < 4; i++)
#pragma unroll
      for (int j = 0; j < 2; j++)
#pragma unroll
        for (int ks = 0; ks < 2; ks++)
          acc[i][j] = __builtin_amdgcn_mfma_f32_16x16x32_bf16(af[i][ks], b01[j][ks], acc[i][j], 0, 0, 0);
    __builtin_amdgcn_s_setprio(0);
    __builtin_amdgcn_s_barrier();
    // ---- P2: stage B-h0(kt+2); read B23; MFMA (i0-3 x j2-3)
    if (kt + 2 < NT) stage_b(kt + 2, cur, 0);
#pragma unroll
    for (int j = 0; j < 2; j++)
#pragma unroll
      for (int ks = 0; ks < 2; ks++) b23[j][ks] = ldB(cur, 2 + j, ks);
    __builtin_amdgcn_s_barrier();
    __builtin_amdgcn_s_setprio(1);
#pragma unroll
    for (int i = 0; i < 4; i++)
#pragma unroll
      for (int j = 0; j < 2; j++)
#pragma unroll
        for (int ks = 0; ks < 2; ks++)
          acc[i][2 + j] = __builtin_amdgcn_mfma_f32_16x16x32_bf16(af[i][ks], b23[j][ks], acc[i][2 + j], 0, 0, 0);
    __builtin_amdgcn_s_setprio(0);
    __builtin_amdgcn_s_barrier();
    // ---- P3: stage B-h1(kt+2); read A q1; MFMA (i4-7 x j2-3)
    if (kt + 2 < NT) stage_b(kt + 2, cur, 1);
#pragma unroll
    for (int i = 0; i < 4; i++)
#pragma unroll
      for (int ks = 0; ks < 2; ks++) af[i][ks] = ldA(cur, 4 + i, ks);
    __builtin_amdgcn_s_barrier();
    __builtin_amdgcn_s_setprio(1);
#pragma unroll
    for (int i = 0; i < 4; i++)
#pragma unroll
      for (int j = 0; j < 2; j++)
#pragma unroll
        for (int ks = 0; ks < 2; ks++)
          acc[4 + i][2 + j] = __builtin_amdgcn_mfma_f32_16x16x32_bf16(af[i][ks], b23[j][ks], acc[4 + i][2 + j], 0, 0, 0);
    __builtin_amdgcn_s_setprio(0);
    __builtin_amdgcn_s_barrier();
    // ---- P4: stage A-lo(kt+2); MFMA (i4-7 x j0-1); counted vmcnt
    if (kt + 2 < NT) stage_a(kt + 2, cur, 0);
    __builtin_amdgcn_s_barrier();
    __builtin_amdgcn_s_setprio(1);
#pragma unroll
    for (int i = 0; i < 4; i++)
#pragma unroll
      for (int j = 0; j < 2; j++)
#pragma unroll
        for (int ks = 0; ks < 2; ks++)
          acc[4 + i][j] = __builtin_amdgcn_mfma_f32_16x16x32_bf16(af[i][ks], b01[j][ks], acc[4 + i][j], 0, 0, 0);
    __builtin_amdgcn_s_setprio(0);
    if (kt + 2 < NT) {
      asm volatile("s_waitcnt vmcnt(6)" ::: "memory");  // kt+1 complete, 3 HT in flight
    } else if (kt + 1 < NT) {
      asm volatile("s_waitcnt vmcnt(0)" ::: "memory");  // drain tail
    }
    __builtin_amdgcn_s_barrier();
  }

  // ============================ epilogue =================================
  bf16* Ts = (bf16*)&smem[0][0];     // EPI2 transpose staging (128 x 264)
  const int colb = bx * 128 + wc * 32;
#pragma unroll
  for (int i = 0; i < 8; i++) {
#pragma unroll
    for (int v = 0; v < 4; v++) {
      const int row = by * 256 + wr * 128 + i * 16 + lq * 4 + v;
      float p1s = 0.f, p2s = 0.f;
#pragma unroll
      for (int jj = 0; jj < 2; jj++) {
        const int col = colb + jj * 16 + lr;
        const long long idx = (long long)row * 512 + col;
        float p0 = acc[i][jj][v] + g.bias_t[col];
        float p1 = acc[i][jj + 2][v] + g.bias_c[col];
        if (EPI == 1) {
          float z = 1.f / (1.f + __expf(-p0));
          float rr = 1.f / (1.f + __expf(-p1));
          float x = (float)((const bf16*)g.xres)[idx];
          ((float*)g.C)[idx] = rr * x + z * z;
        } else {
          float tt = fmaxf(p0, 0.f);
          float c = 1.f / (1.f + __expf(-p1));
          float x = (float)((const bf16*)g.xres)[idx];
          bf16 xn = (bf16)(tt * c + x * (1.f - c));
          ((bf16*)g.C)[idx] = xn;
          if (EPI == 2) {
            float xf = (float)xn;
            p1s += xf * g.aW[col];
            p2s += xf * g.aW[512 + col];
            g.q[idx] = (bf16)(xf * g.aW[1024 + col]);
            Ts[(wc * 32 + jj * 16 + lr) * 264 + (wr * 128 + i * 16 + lq * 4 + v)] = xn;
          }
        }
      }
      if (EPI == 2) {
        p1s += __shfl_xor(p1s, 1, 64);
        p1s += __shfl_xor(p1s, 2, 64);
        p1s += __shfl_xor(p1s, 4, 64);
        p1s += __shfl_xor(p1s, 8, 64);
        p2s += __shfl_xor(p2s, 1, 64);
        p2s += __shfl_xor(p2s, 2, 64);
        p2s += __shfl_xor(p2s, 4, 64);
        p2s += __shfl_xor(p2s, 8, 64);
        if (lr == 0) {
          atomicAdd(&g.s1a[row], p1s);
          atomicAdd(&g.s2a[row], p2s);
        }
      }
    }
  }

  if (EPI == 2) {
    // coalesced xT writeout of the 256(j) x 128(d) tile staged in Ts
    __syncthreads();
    const int b = by >> 2;
    const long long j0 = (long long)(by & 3) * 256;
    bf16* dst = g.xT + (long long)b * 524288;
    const int dloc = tid >> 2;          // 0..127
    const int jb = (tid & 3) * 64;
#pragma unroll
    for (int it = 0; it < 4; it++) {
      const int j = jb + it * 16;
      bf16x8 v0 = *(const bf16x8*)(&Ts[dloc * 264 + j]);
      bf16x8 v1 = *(const bf16x8*)(&Ts[dloc * 264 + j + 8]);
      long long o = (long long)(bx * 128 + dloc) * 1024 + j0 + j;
      *(bf16x8*)(dst + o) = v0;
      *(bf16x8*)(dst + o + 8) = v1;
    }
  }
}

// ============================ prep kernel ==================================
// Block-segmented:
//   [0,256)      : w1T = [tW|cW]^T via 64x64 LDS-tiled transpose (coalesced)
//   [256,512)    : w2T = [ffW|frW]^T likewise
//   [512,4608)   : fp32 inputs -> bf16 xb0 (coalesced; 4096 blocks)
//   [4608]       : biases + sred zeroing
__device__ __forceinline__ void tile_transpose(const float* src, int sld,
                                               bf16* dst, int dld,
                                               int k0, int n0, int tid) {
  __shared__ float tile[64][65];
  const int rr = tid >> 4, c4 = (tid & 15) * 4;
#pragma unroll
  for (int it = 0; it < 4; it++) {
    int r = rr + it * 16;
    f32x4 v = *(const f32x4*)(src + (long long)(k0 + r) * sld + n0 + c4);
    tile[r][c4] = v[0]; tile[r][c4 + 1] = v[1];
    tile[r][c4 + 2] = v[2]; tile[r][c4 + 3] = v[3];
  }
  __syncthreads();
  const int nl = tid >> 2, kb = (tid & 3) * 16;
  bf16x8 o0, o1;
#pragma unroll
  for (int kk = 0; kk < 8; kk++) o0[kk] = (bf16)tile[kb + kk][nl];
#pragma unroll
  for (int kk = 0; kk < 8; kk++) o1[kk] = (bf16)tile[kb + 8 + kk][nl];
  bf16* d = dst + (long long)(n0 + nl) * dld + k0 + kb;
  *(bf16x8*)d = o0;
  *(bf16x8*)(d + 8) = o1;
}

__global__ void prep(const float* tW, const float* tb, const float* cW, const float* cb,
                     const float* frW, const float* frb, const float* ffW, const float* ffb,
                     const float* inp, bf16* xb0,
                     bf16* w1T, bf16* w2T, float* bias1, float* bias2, float* sred) {
  const int bid = blockIdx.x, tid = threadIdx.x;
  if (bid < 256) {
    const int quad = bid >> 6, tile = bid & 63;
    const int l = quad >> 1, half = quad & 1;
    const float* src = (half ? cW : tW) + l * 262144;
    bf16* dst = w1T + l * 524288 + half * 262144;
    tile_transpose(src, 512, dst, 512, (tile >> 3) * 64, (tile & 7) * 64, tid);
  } else if (bid < 512) {
    const int j = bid - 256;
    const int half = j >> 7, tile = j & 127;
    const float* src = half ? frW : ffW;
    bf16* dst = w2T + half * 524288;
    tile_transpose(src, 512, dst, 1024, (tile >> 3) * 64, (tile & 7) * 64, tid);
  } else if (bid < 4608) {
    long long i8 = (((long long)(bid - 512)) * 256 + tid) * 8;
    bf16x8 o;
#pragma unroll
    for (int k = 0; k < 8; k++) o[k] = (bf16)inp[i8 + k];
    *(bf16x8*)(xb0 + i8) = o;
  } else {
    for (int j = tid; j < 3072; j += 256) {
      if (j < 2048) {
        int l = j >> 10, n = j & 1023;
        bias1[j] = (n < 512) ? tb[l * 512 + n] : cb[l * 512 + (n - 512)];
      } else {
        int n = j - 2048;
        bias2[n] = (n < 512) ? ffb[n] : frb[n - 512];
      }
    }
    for (int j = tid; j < 12288; j += 256)
      *(f32x4*)(sred + j * 4) = f32x4{0.f, 0.f, 0.f, 0.f};
  }
}

extern "C" void kernel_launch(void* const* d_in, const int* in_sizes, int n_in,
                              void* d_out, int out_size, void* d_ws, size_t ws_size,
                              hipStream_t stream) {
  const float* inp = (const float*)d_in[0];
  const float* tW  = (const float*)d_in[1];
  const float* tb  = (const float*)d_in[2];
  const float* cW  = (const float*)d_in[3];
  const float* cb  = (const float*)d_in[4];
  const float* aW  = (const float*)d_in[5];
  const float* ab  = (const float*)d_in[6];
  const float* frW = (const float*)d_in[7];
  const float* frb = (const float*)d_in[8];
  const float* ffW = (const float*)d_in[9];
  const float* ffb = (const float*)d_in[10];
  float* out = (float*)d_out;

  char* p = (char*)d_ws;
  auto alloc = [&](size_t bytes) { char* r = p; p += (bytes + 255) & ~size_t(255); return r; };
  bf16* xb0   = (bf16*) alloc(16777216);
  bf16* x1    = (bf16*) alloc(16777216);
  bf16* x2    = (bf16*) alloc(16777216);
  bf16* q16   = (bf16*) alloc(16777216);
  bf16* xT16  = (bf16*) alloc(16777216);
  bf16* att16 = (bf16*) alloc(16777216);
  bf16* E16   = (bf16*) alloc(33554432);
  float* sred = (float*)alloc(196608);     // s1 | s2 | lsum
  bf16* w1T   = (bf16*) alloc(2097152);
  bf16* w2T   = (bf16*) alloc(2097152);
  float* bias1= (float*)alloc(8192);
  float* bias2= (float*)alloc(4096);
  float* s1 = sred, *s2 = sred + 16384, *lsum = sred + 32768;

  prep<<<4609, 256, 0, stream>>>(
      tW, tb, cW, cb, frW, frb, ffW, ffb, inp, xb0, w1T, w2T, bias1, bias2, sred);

  {  // highway 1
    DualArgs g{};
    g.A = xb0; g.A2 = xb0; g.Bt = w1T;
    g.C = x1; g.xres = xb0;
    g.bias_t = bias1; g.bias_c = bias1 + 512;
    g.K = 512; g.ldb = 512;
    gemm_dual8<0><<<256, 512, 0, stream>>>(g);
  }
  {  // highway 2 + fused s1/s2/q + fused transpose
    DualArgs g{};
    g.A = x1; g.A2 = x1; g.Bt = w1T + 524288;
    g.C = x2; g.xres = x1;
    g.bias_t = bias1 + 1024; g.bias_c = bias1 + 1536;
    g.K = 512; g.ldb = 512;
    g.aW = aW; g.s1a = s1; g.s2a = s2; g.q = q16; g.xT = xT16;
    gemm_dual8<2><<<256, 512, 0, stream>>>(g);
  }
  {  // scores: E = exp(relu(Q K^T + s1 + s2 + ab)), row sums into lsum
    GemmArgs g{};
    g.A = q16; g.B = x2; g.C = E16;
    g.K = 512; g.lda = 512; g.ldb = 512; g.ldc = 1024;
    g.Ab = 524288; g.Bb = 524288; g.Cb = 1048576;
    g.s1 = s1; g.s2 = s2; g.abp = ab; g.lsum = lsum; g.L = 1024;
    g.gxsh = 3; g.gysh = 3;
    gemm_nt<1, 128><<<1024, 256, 0, stream>>>(g);
  }
  {  // att = (E @ x) / l -> att16   (128x64 tiles, 1024 blocks = 4/CU)
    GemmArgs g{};
    g.A = E16; g.B = xT16; g.C = att16;
    g.K = 1024; g.lda = 1024; g.ldb = 1024; g.ldc = 512;
    g.Ab = 1048576; g.Bb = 524288; g.Cb = 524288;
    g.s1 = lsum; g.L = 1024;
    g.gxsh = 3; g.gysh = 3;
    gemm_nt<4, 64><<<1024, 256, 0, stream>>>(g);
  }
  {  // final: out = r*x + z*z, z/r = sigmoid([xb0|att] @ [ffW|frW] + b)
    DualArgs g{};
    g.A = xb0; g.A2 = att16; g.Bt = w2T;
    g.C = out; g.xres = xb0;               // bf16 residual
    g.bias_t = bias2; g.bias_c = bias2 + 512;
    g.K = 1024; g.ldb = 1024;
    gemm_dual8<1><<<256, 512, 0, stream>>>(g);
  }
}